// Round 2
// baseline (3180.071 us; speedup 1.0000x reference)
//
#include <hip/hip_runtime.h>

// RGCNConv: out_i = x_i @ W_root + bias + sum_r mean_{j in N_r(i)} x_j @ W_r
//
// Small-workspace, transform-first, column-chunked:
//   cnt[dst*R+t] += 1  ->  invc = 1/max(cnt,1)
//   out = x @ W_root + bias
//   for each column chunk c0 of width CC:
//     y[n, r*CC+cc] = sum_k x[n,k] * W[r,k,c0+cc]     (one GEMM, all relations)
//     for each edge: out[dst, c0+cc] += invc[dst,t] * y[src, t*CC+cc]
//
// CC adapts to ws_size: largest of {128,64,32,16,8,4} that fits.

constexpr int D  = 128;
constexpr int R  = 8;
constexpr int BM = 64;
constexpr int BK = 32;

__global__ __launch_bounds__(256)
void cnt_kernel(const int* __restrict__ dst, const int* __restrict__ et,
                float* __restrict__ cnt, int E) {
    int e = blockIdx.x * 256 + threadIdx.x;
    if (e < E) atomicAdd(&cnt[dst[e] * R + et[e]], 1.0f);
}

__global__ __launch_bounds__(256)
void invcnt_kernel(float* __restrict__ cnt, int n) {
    int i = blockIdx.x * 256 + threadIdx.x;
    if (i < n) cnt[i] = 1.0f / fmaxf(cnt[i], 1.0f);
}

// C = x @ B (+bias).  ROOT: B = W_root [128][128], write out[N][128].
// !ROOT: output col jg -> r=jg/CC, cc=jg%CC, B[k][jg] = W[r][k][c0+cc]; write y[N][R*CC].
template<int BN, bool ROOT>
__global__ __launch_bounds__(256)
void gemm_kernel(const float* __restrict__ x,
                 const float* __restrict__ Bw,
                 const float* __restrict__ bias,
                 float* __restrict__ outp,
                 int N, int CC, int c0) {
    constexpr int TXg = BN / 4;       // col groups of 4
    constexpr int TYg = 256 / TXg;    // row groups
    constexpr int MR  = BM / TYg;     // rows per thread
    __shared__ float As[BK][BM + 4];
    __shared__ float Bs[BK][BN + 4];

    const int tid  = threadIdx.x;
    const int row0 = blockIdx.x * BM;
    const int jg0  = blockIdx.y * BN;
    const int tx   = tid % TXg;
    const int ty   = tid / TXg;
    const int ldy  = ROOT ? D : R * CC;

    float acc[MR][4] = {};

    for (int kt = 0; kt < D; kt += BK) {
        // ---- stage B tile: BK x BN ----
        constexpr int NB4 = (BK * BN) / (4 * 256);
        #pragma unroll
        for (int i = 0; i < NB4; ++i) {
            int idx = tid + i * 256;
            int kk  = idx / (BN / 4);
            int c4  = idx % (BN / 4);
            int jg  = jg0 + c4 * 4;
            const float* bp;
            if (ROOT) {
                bp = Bw + (size_t)(kt + kk) * D + jg;
            } else {
                int r  = jg / CC;
                int cc = jg % CC;     // float4 stays inside one relation (CC>=4, jg%4==0)
                bp = Bw + (size_t)r * (D * D) + (size_t)(kt + kk) * D + c0 + cc;
            }
            *(float4*)&Bs[kk][c4 * 4] = *(const float4*)bp;
        }
        // ---- stage A tile: BM x BK (transposed into LDS) ----
        #pragma unroll
        for (int i = 0; i < 2; ++i) {
            int idx  = tid + i * 256;
            int m    = idx >> 3;
            int k4   = idx & 7;
            int node = row0 + m;
            float4 v = make_float4(0.f, 0.f, 0.f, 0.f);
            if (node < N) v = *(const float4*)(x + (size_t)node * D + kt + k4 * 4);
            As[k4 * 4 + 0][m] = v.x;
            As[k4 * 4 + 1][m] = v.y;
            As[k4 * 4 + 2][m] = v.z;
            As[k4 * 4 + 3][m] = v.w;
        }
        __syncthreads();

        #pragma unroll
        for (int kk = 0; kk < BK; ++kk) {
            float a[MR];
            #pragma unroll
            for (int i = 0; i < MR; ++i) a[i] = As[kk][ty * MR + i];
            float4 b = *(const float4*)&Bs[kk][tx * 4];
            #pragma unroll
            for (int i = 0; i < MR; ++i) {
                acc[i][0] = fmaf(a[i], b.x, acc[i][0]);
                acc[i][1] = fmaf(a[i], b.y, acc[i][1]);
                acc[i][2] = fmaf(a[i], b.z, acc[i][2]);
                acc[i][3] = fmaf(a[i], b.w, acc[i][3]);
            }
        }
        __syncthreads();
    }

    float4 bv = make_float4(0.f, 0.f, 0.f, 0.f);
    if (ROOT) bv = *(const float4*)(bias + tx * 4);
    #pragma unroll
    for (int i = 0; i < MR; ++i) {
        int node = row0 + ty * MR + i;
        if (node < N) {
            float4 o = make_float4(acc[i][0] + bv.x, acc[i][1] + bv.y,
                                   acc[i][2] + bv.z, acc[i][3] + bv.w);
            *(float4*)(outp + (size_t)node * ldy + jg0 + tx * 4) = o;
        }
    }
}

// One edge pass per chunk: out[dst, c0 + q*4 ..] += invc[dst,t] * y[src, t*CC + q*4 ..]
__global__ __launch_bounds__(256)
void scatter_kernel(const float* __restrict__ y,
                    const int* __restrict__ src, const int* __restrict__ dst,
                    const int* __restrict__ et, const float* __restrict__ invc,
                    float* __restrict__ out, int E, int CC, int c0) {
    int tpe = CC / 4;                     // threads per edge (1 float4 each)
    int epb = 256 / tpe;                  // edges per block
    int e   = blockIdx.x * epb + threadIdx.x / tpe;
    int q   = threadIdx.x % tpe;
    if (e >= E) return;
    int s = src[e], dd = dst[e], t = et[e];
    float sc = invc[dd * R + t];
    float4 v = *(const float4*)(y + (size_t)s * (R * CC) + t * CC + q * 4);
    float* op = out + (size_t)dd * D + c0 + q * 4;
    atomicAdd(op + 0, v.x * sc);
    atomicAdd(op + 1, v.y * sc);
    atomicAdd(op + 2, v.z * sc);
    atomicAdd(op + 3, v.w * sc);
}

extern "C" void kernel_launch(void* const* d_in, const int* in_sizes, int n_in,
                              void* d_out, int out_size, void* d_ws, size_t ws_size,
                              hipStream_t stream) {
    const float* x     = (const float*)d_in[0];
    const float* W     = (const float*)d_in[1];
    const float* Wroot = (const float*)d_in[2];
    const float* bias  = (const float*)d_in[3];
    const int*   ei    = (const int*)d_in[4];
    const int*   et    = (const int*)d_in[5];
    float*       out   = (float*)d_out;

    const int N = in_sizes[0] / D;
    const int E = in_sizes[5];
    const int* src = ei;
    const int* dst = ei + E;

    const size_t cnt_elems = (size_t)N * R;

    // pick the largest chunk width that fits ws
    int CC = 0;
    const int cands[6] = {128, 64, 32, 16, 8, 4};
    for (int i = 0; i < 6; ++i) {
        size_t need = ((size_t)N * R * cands[i] + cnt_elems) * sizeof(float);
        if (need <= ws_size) { CC = cands[i]; break; }
    }
    if (CC == 0) return;   // ws < 16 MB: not handled (diagnose via absmax=|ref|max)

    float* y   = (float*)d_ws;
    float* cnt = y + (size_t)N * R * CC;

    hipMemsetAsync(cnt, 0, cnt_elems * sizeof(float), stream);
    cnt_kernel<<<(E + 255) / 256, 256, 0, stream>>>(dst, et, cnt, E);
    invcnt_kernel<<<(int)((cnt_elems + 255) / 256), 256, 0, stream>>>(cnt, (int)cnt_elems);

    const int gx = (N + BM - 1) / BM;
    gemm_kernel<128, true><<<dim3(gx, 1), 256, 0, stream>>>(x, Wroot, bias, out, N, D, 0);

    const int nchunks = D / CC;
    for (int c = 0; c < nchunks; ++c) {
        int c0 = c * CC;
        int totcols = R * CC;
        if (totcols >= 128) {
            gemm_kernel<128, false><<<dim3(gx, totcols / 128), 256, 0, stream>>>(x, W, nullptr, y, N, CC, c0);
        } else if (totcols == 64) {
            gemm_kernel<64, false><<<dim3(gx, 1), 256, 0, stream>>>(x, W, nullptr, y, N, CC, c0);
        } else {
            gemm_kernel<32, false><<<dim3(gx, 1), 256, 0, stream>>>(x, W, nullptr, y, N, CC, c0);
        }
        int tpe = CC / 4;
        int epb = 256 / tpe;
        scatter_kernel<<<(E + epb - 1) / epb, 256, 0, stream>>>(y, src, dst, et, cnt, out, E, CC, c0);
    }
}

// Round 3
// 1014.786 us; speedup vs baseline: 3.1337x; 3.1337x over previous
//
#include <hip/hip_runtime.h>

// RGCNConv: out_i = x_i @ W_root + bias + sum_r mean_{j in N_r(i)} x_j @ W_r
//
// Transform-first, column-chunked, SORTED-GATHER aggregation (no fp32 atomics):
//   1. hist[dst]++, cnt[dst*R+t]++  (int/float atomics, small L2-resident arrays)
//   2. invc = 1/max(cnt,1)
//   3. exclusive-scan hist -> start[], cursor[]
//   4. reorder: spack[pos] = src | (type<<24), pos = cursor[dst]++  (edges grouped by dst)
//   5. out = x @ W_root + bias
//   6. per column chunk c0 (width CC):
//        y[n, r*CC+cc] = sum_k x[n,k] * W[r,k,c0+cc]   (one GEMM, all relations)
//        gather: out[dst, c0+col] += sum_{e in edges(dst)} invc[dst,t_e]*y[src_e, t_e*CC+col]
//                (one thread owns one (dst,col) -> no atomics)

constexpr int D  = 128;
constexpr int R  = 8;
constexpr int BM = 64;
constexpr int BK = 32;

// ---- phase 1: histogram over dst + per-(dst,rel) float counts ----
__global__ __launch_bounds__(256)
void hist_cnt_kernel(const int* __restrict__ dst, const int* __restrict__ et,
                     int* __restrict__ hist, float* __restrict__ cnt, int E) {
    int e = blockIdx.x * 256 + threadIdx.x;
    if (e < E) {
        int d = dst[e];
        atomicAdd(&hist[d], 1);
        atomicAdd(&cnt[d * R + et[e]], 1.0f);
    }
}

__global__ __launch_bounds__(256)
void invcnt_kernel(float* __restrict__ cnt, int n) {
    int i = blockIdx.x * 256 + threadIdx.x;
    if (i < n) cnt[i] = 1.0f / fmaxf(cnt[i], 1.0f);
}

// ---- phase 3a: per-block sums of hist ----
__global__ __launch_bounds__(256)
void block_sums_kernel(const int* __restrict__ hs, int* __restrict__ bsum, int N) {
    __shared__ int sh[256];
    int i = blockIdx.x * 256 + threadIdx.x;
    sh[threadIdx.x] = (i < N) ? hs[i] : 0;
    __syncthreads();
    for (int off = 128; off > 0; off >>= 1) {
        if (threadIdx.x < off) sh[threadIdx.x] += sh[threadIdx.x + off];
        __syncthreads();
    }
    if (threadIdx.x == 0) bsum[blockIdx.x] = sh[0];
}

// ---- phase 3b: single-wave exclusive scan of block sums ----
__global__ __launch_bounds__(64)
void scan_bsum_kernel(int* __restrict__ bsum, int nb) {
    int lane = threadIdx.x;
    int carry = 0;
    for (int base = 0; base < nb; base += 64) {
        int i = base + lane;
        int orig = (i < nb) ? bsum[i] : 0;
        int v = orig;
        #pragma unroll
        for (int off = 1; off < 64; off <<= 1) {
            int u = __shfl_up(v, off, 64);
            if (lane >= off) v += u;
        }
        int tot = __shfl(v, 63, 64);
        if (i < nb) bsum[i] = carry + (v - orig);   // exclusive
        carry += tot;
    }
}

// ---- phase 3c: in-block exclusive scan + base -> start[], cursor[] ----
__global__ __launch_bounds__(256)
void scan_block_kernel(int* __restrict__ hs, const int* __restrict__ bsum,
                       int* __restrict__ cursor, int N, int E) {
    __shared__ int sh[256];
    int tid = threadIdx.x;
    int i = blockIdx.x * 256 + tid;
    int v = (i < N) ? hs[i] : 0;
    sh[tid] = v;
    __syncthreads();
    for (int off = 1; off < 256; off <<= 1) {
        int u = (tid >= off) ? sh[tid - off] : 0;
        __syncthreads();
        sh[tid] += u;
        __syncthreads();
    }
    int st = bsum[blockIdx.x] + sh[tid] - v;   // exclusive prefix
    if (i < N) { hs[i] = st; cursor[i] = st; }
    if (i == N) hs[N] = E;
}

// ---- phase 4: place edges contiguous by dst ----
__global__ __launch_bounds__(256)
void reorder_kernel(const int* __restrict__ src, const int* __restrict__ dst,
                    const int* __restrict__ et, int* __restrict__ cursor,
                    int* __restrict__ spack, int E) {
    int e = blockIdx.x * 256 + threadIdx.x;
    if (e < E) {
        int pos = atomicAdd(&cursor[dst[e]], 1);
        spack[pos] = src[e] | (et[e] << 24);
    }
}

// ---- phase 5/6a: C = x @ B (+bias). ROOT: B=W_root, out[N][128].
// !ROOT: col jg -> r=jg/CC, cc=jg%CC, B[k][jg]=W[r][k][c0+cc]; write y[N][R*CC].
template<int BN, bool ROOT>
__global__ __launch_bounds__(256)
void gemm_kernel(const float* __restrict__ x,
                 const float* __restrict__ Bw,
                 const float* __restrict__ bias,
                 float* __restrict__ outp,
                 int N, int CC, int c0) {
    constexpr int TXg = BN / 4;
    constexpr int TYg = 256 / TXg;
    constexpr int MR  = BM / TYg;
    __shared__ float As[BK][BM + 4];
    __shared__ float Bs[BK][BN + 4];

    const int tid  = threadIdx.x;
    const int row0 = blockIdx.x * BM;
    const int jg0  = blockIdx.y * BN;
    const int tx   = tid % TXg;
    const int ty   = tid / TXg;
    const int ldy  = ROOT ? D : R * CC;

    float acc[MR][4] = {};

    for (int kt = 0; kt < D; kt += BK) {
        constexpr int NB4 = (BK * BN) / (4 * 256);
        #pragma unroll
        for (int i = 0; i < NB4; ++i) {
            int idx = tid + i * 256;
            int kk  = idx / (BN / 4);
            int c4  = idx % (BN / 4);
            int jg  = jg0 + c4 * 4;
            const float* bp;
            if (ROOT) {
                bp = Bw + (size_t)(kt + kk) * D + jg;
            } else {
                int r  = jg / CC;
                int cc = jg % CC;
                bp = Bw + (size_t)r * (D * D) + (size_t)(kt + kk) * D + c0 + cc;
            }
            *(float4*)&Bs[kk][c4 * 4] = *(const float4*)bp;
        }
        #pragma unroll
        for (int i = 0; i < 2; ++i) {
            int idx  = tid + i * 256;
            int m    = idx >> 3;
            int k4   = idx & 7;
            int node = row0 + m;
            float4 v = make_float4(0.f, 0.f, 0.f, 0.f);
            if (node < N) v = *(const float4*)(x + (size_t)node * D + kt + k4 * 4);
            As[k4 * 4 + 0][m] = v.x;
            As[k4 * 4 + 1][m] = v.y;
            As[k4 * 4 + 2][m] = v.z;
            As[k4 * 4 + 3][m] = v.w;
        }
        __syncthreads();

        #pragma unroll
        for (int kk = 0; kk < BK; ++kk) {
            float a[MR];
            #pragma unroll
            for (int i = 0; i < MR; ++i) a[i] = As[kk][ty * MR + i];
            float4 b = *(const float4*)&Bs[kk][tx * 4];
            #pragma unroll
            for (int i = 0; i < MR; ++i) {
                acc[i][0] = fmaf(a[i], b.x, acc[i][0]);
                acc[i][1] = fmaf(a[i], b.y, acc[i][1]);
                acc[i][2] = fmaf(a[i], b.z, acc[i][2]);
                acc[i][3] = fmaf(a[i], b.w, acc[i][3]);
            }
        }
        __syncthreads();
    }

    float4 bv = make_float4(0.f, 0.f, 0.f, 0.f);
    if (ROOT) bv = *(const float4*)(bias + tx * 4);
    #pragma unroll
    for (int i = 0; i < MR; ++i) {
        int node = row0 + ty * MR + i;
        if (node < N) {
            float4 o = make_float4(acc[i][0] + bv.x, acc[i][1] + bv.y,
                                   acc[i][2] + bv.z, acc[i][3] + bv.w);
            *(float4*)(outp + (size_t)node * ldy + jg0 + tx * 4) = o;
        }
    }
}

// ---- phase 6b: gather-aggregate. One thread owns (node, col). No atomics. ----
__global__ __launch_bounds__(256)
void gather_kernel(const float* __restrict__ y,
                   const int* __restrict__ spack,
                   const int* __restrict__ start,
                   const int* __restrict__ endc,   // cursor after reorder == end
                   const float* __restrict__ invc,
                   float* __restrict__ out,
                   int N, int ccshift, int c0) {
    int CCm = (1 << ccshift) - 1;
    int idx = blockIdx.x * 256 + threadIdx.x;
    int node = idx >> ccshift;
    int col  = idx & CCm;
    if (node >= N) return;
    int p0 = start[node], p1 = endc[node];
    float acc = 0.0f;
    for (int p = p0; p < p1; ++p) {
        int pk = spack[p];
        int s  = pk & 0xFFFFFF;
        int t  = pk >> 24;
        float sc = invc[node * R + t];
        acc = fmaf(sc, y[((size_t)s << (ccshift + 3)) + (t << ccshift) + col], acc);
    }
    out[(size_t)node * D + c0 + col] += acc;
}

extern "C" void kernel_launch(void* const* d_in, const int* in_sizes, int n_in,
                              void* d_out, int out_size, void* d_ws, size_t ws_size,
                              hipStream_t stream) {
    const float* x     = (const float*)d_in[0];
    const float* W     = (const float*)d_in[1];
    const float* Wroot = (const float*)d_in[2];
    const float* bias  = (const float*)d_in[3];
    const int*   ei    = (const int*)d_in[4];
    const int*   et    = (const int*)d_in[5];
    float*       out   = (float*)d_out;

    const int N = in_sizes[0] / D;
    const int E = in_sizes[5];
    const int* src = ei;
    const int* dst = ei + E;

    const size_t cnt_elems = (size_t)N * R;
    const int NB = (N + 256) / 256;                 // covers i in [0, N]
    const size_t fixed_ints = (size_t)(N + 1) + N + E + NB;

    // pick the largest chunk width that fits ws
    int CC = 0, ccshift = 0;
    const int cands[6]  = {128, 64, 32, 16, 8, 4};
    const int cshift[6] = {7, 6, 5, 4, 3, 2};
    for (int i = 0; i < 6; ++i) {
        size_t need = ((size_t)N * R * cands[i] + cnt_elems + fixed_ints) * sizeof(float);
        if (need <= ws_size) { CC = cands[i]; ccshift = cshift[i]; break; }
    }
    if (CC == 0) return;

    float* y      = (float*)d_ws;
    float* cnt    = y + (size_t)N * R * CC;
    int*   hstart = (int*)(cnt + cnt_elems);        // hist -> start, N+1 ints
    int*   cursor = hstart + (N + 1);
    int*   spack  = cursor + N;
    int*   bsum   = spack + E;

    hipMemsetAsync(cnt, 0, cnt_elems * sizeof(float), stream);
    hipMemsetAsync(hstart, 0, (N + 1) * sizeof(int), stream);

    hist_cnt_kernel<<<(E + 255) / 256, 256, 0, stream>>>(dst, et, hstart, cnt, E);
    invcnt_kernel<<<(int)((cnt_elems + 255) / 256), 256, 0, stream>>>(cnt, (int)cnt_elems);

    block_sums_kernel<<<NB, 256, 0, stream>>>(hstart, bsum, N);
    scan_bsum_kernel<<<1, 64, 0, stream>>>(bsum, NB);
    scan_block_kernel<<<NB, 256, 0, stream>>>(hstart, bsum, cursor, N, E);
    reorder_kernel<<<(E + 255) / 256, 256, 0, stream>>>(src, dst, et, cursor, spack, E);

    const int gx = (N + BM - 1) / BM;
    gemm_kernel<128, true><<<dim3(gx, 1), 256, 0, stream>>>(x, Wroot, bias, out, N, D, 0);

    const int nchunks = D / CC;
    for (int c = 0; c < nchunks; ++c) {
        int c0 = c * CC;
        int totcols = R * CC;
        if (totcols >= 128) {
            gemm_kernel<128, false><<<dim3(gx, totcols / 128), 256, 0, stream>>>(x, W, nullptr, y, N, CC, c0);
        } else if (totcols == 64) {
            gemm_kernel<64, false><<<dim3(gx, 1), 256, 0, stream>>>(x, W, nullptr, y, N, CC, c0);
        } else {
            gemm_kernel<32, false><<<dim3(gx, 1), 256, 0, stream>>>(x, W, nullptr, y, N, CC, c0);
        }
        int gblocks = (int)(((size_t)N * CC + 255) / 256);
        gather_kernel<<<gblocks, 256, 0, stream>>>(y, spack, hstart, cursor, cnt, out, N, ccshift, c0);
    }
}

// Round 4
// 484.036 us; speedup vs baseline: 6.5699x; 2.0965x over previous
//
#include <hip/hip_runtime.h>

// RGCNConv: out_i = x_i @ W_root + bias + sum_r mean_{j in N_r(i)} x_j @ W_r
//
// AGGREGATE-FIRST + bf16 MFMA finalize:
//   1. sort edges by seg = dst*R + type (hist -> scan -> reorder), counts = CSR range len
//   2. aggregate: mean_bf[seg][cc] = bf16( (1/cnt) * sum_edges x[src][c0+cc] )
//   3. one MFMA GEMM: out[N,128] = [x_bf | mean_bf] @ WallT_bf (+bias)
//   mean feature dim chunked by CW (128/64/32/16) to fit ws_size; pass c>0 does out +=.

constexpr int D = 128;
constexpr int R = 8;

typedef __bf16 bf16x8 __attribute__((ext_vector_type(8)));
typedef float  f32x4  __attribute__((ext_vector_type(4)));
typedef unsigned short u16x8 __attribute__((ext_vector_type(8)));
typedef unsigned short u16x4 __attribute__((ext_vector_type(4)));

__device__ __forceinline__ unsigned short f2bf(float f) {
    unsigned u = __builtin_bit_cast(unsigned, f);
    u += 0x7FFFu + ((u >> 16) & 1u);          // round-to-nearest-even
    return (unsigned short)(u >> 16);
}

// ---- sort phase ----
__global__ __launch_bounds__(256)
void hist_kernel(const int* __restrict__ dst, const int* __restrict__ et,
                 int* __restrict__ hist, int E) {
    int e = blockIdx.x * 256 + threadIdx.x;
    if (e < E) atomicAdd(&hist[dst[e] * R + et[e]], 1);
}

__global__ __launch_bounds__(256)
void block_sums_kernel(const int* __restrict__ hs, int* __restrict__ bsum, int n) {
    __shared__ int sh[256];
    int i = blockIdx.x * 256 + threadIdx.x;
    sh[threadIdx.x] = (i < n) ? hs[i] : 0;
    __syncthreads();
    for (int off = 128; off > 0; off >>= 1) {
        if (threadIdx.x < off) sh[threadIdx.x] += sh[threadIdx.x + off];
        __syncthreads();
    }
    if (threadIdx.x == 0) bsum[blockIdx.x] = sh[0];
}

__global__ __launch_bounds__(64)
void scan_bsum_kernel(int* __restrict__ bsum, int nb) {
    int lane = threadIdx.x;
    int carry = 0;
    for (int base = 0; base < nb; base += 64) {
        int i = base + lane;
        int orig = (i < nb) ? bsum[i] : 0;
        int v = orig;
        #pragma unroll
        for (int off = 1; off < 64; off <<= 1) {
            int u = __shfl_up(v, off, 64);
            if (lane >= off) v += u;
        }
        int tot = __shfl(v, 63, 64);
        if (i < nb) bsum[i] = carry + (v - orig);
        carry += tot;
    }
}

__global__ __launch_bounds__(256)
void scan_block_kernel(int* __restrict__ hs, const int* __restrict__ bsum,
                       int* __restrict__ cursor, int n, int E) {
    __shared__ int sh[256];
    int tid = threadIdx.x;
    int i = blockIdx.x * 256 + tid;
    int v = (i < n) ? hs[i] : 0;
    sh[tid] = v;
    __syncthreads();
    for (int off = 1; off < 256; off <<= 1) {
        int u = (tid >= off) ? sh[tid - off] : 0;
        __syncthreads();
        sh[tid] += u;
        __syncthreads();
    }
    int st = bsum[blockIdx.x] + sh[tid] - v;
    if (i < n) { hs[i] = st; cursor[i] = st; }
    if (i == n) hs[n] = E;
}

__global__ __launch_bounds__(256)
void reorder_kernel(const int* __restrict__ src, const int* __restrict__ dst,
                    const int* __restrict__ et, int* __restrict__ cursor,
                    int* __restrict__ spack, int E) {
    int e = blockIdx.x * 256 + threadIdx.x;
    if (e < E) {
        int pos = atomicAdd(&cursor[dst[e] * R + et[e]], 1);
        spack[pos] = src[e];
    }
}

// ---- aggregate: mean_bf[seg][CW] for feature cols [c0, c0+CW) ----
__global__ __launch_bounds__(256)
void aggregate_kernel(const float* __restrict__ x, const int* __restrict__ spack,
                      const int* __restrict__ hstart, unsigned short* __restrict__ mean,
                      int nseg, int tshift, int c0) {
    int idx = blockIdx.x * 256 + threadIdx.x;
    int seg = idx >> tshift;                      // CW/4 threads per seg
    int c4  = idx & ((1 << tshift) - 1);
    if (seg >= nseg) return;
    int p0 = hstart[seg], p1 = hstart[seg + 1];
    float a0 = 0.f, a1 = 0.f, a2 = 0.f, a3 = 0.f;
    for (int p = p0; p < p1; ++p) {
        int s = spack[p];
        float4 v = *(const float4*)(x + ((size_t)s << 7) + c0 + (c4 << 2));
        a0 += v.x; a1 += v.y; a2 += v.z; a3 += v.w;
    }
    float sc = (p1 > p0) ? (1.0f / (float)(p1 - p0)) : 0.0f;
    u16x4 o;
    o[0] = f2bf(a0 * sc); o[1] = f2bf(a1 * sc);
    o[2] = f2bf(a2 * sc); o[3] = f2bf(a3 * sc);
    *(u16x4*)(mean + ((size_t)seg << (tshift + 2)) + (c4 << 2)) = o;
}

// ---- build transposed bf16 weight block for one pass ----
// WallTc[n][kk], kk < KW. first: kk<128 -> Wroot[kk][n]; else lk=kk-128*first,
// r=lk/CW, cc=lk%CW -> W[r][c0+cc][n]
__global__ __launch_bounds__(256)
void wallt_kernel(const float* __restrict__ Wroot, const float* __restrict__ W,
                  unsigned short* __restrict__ WallTc, int KW, int CW, int c0, int first) {
    int idx = blockIdx.x * 256 + threadIdx.x;
    if (idx >= 128 * KW) return;
    int n = idx / KW, kk = idx % KW;
    float v;
    if (first && kk < 128) {
        v = Wroot[kk * 128 + n];
    } else {
        int lk = kk - (first ? 128 : 0);
        int r = lk / CW, cc = lk % CW;
        v = W[((size_t)r * 128 + c0 + cc) * 128 + n];
    }
    WallTc[idx] = f2bf(v);
}

// ---- MFMA GEMM: out[128-tile][128] (+)= A_virtual @ WallTc ----
// A cols: FIRST && kt<4 -> bf16(x[node][kt*32..]); else mean[node*MROW + (kt-4*FIRST)*32..]
template<bool FIRST>
__global__ __launch_bounds__(256)
void mfma_gemm_kernel(const float* __restrict__ x,
                      const unsigned short* __restrict__ mean,
                      const unsigned short* __restrict__ WallTc,
                      const float* __restrict__ bias,
                      float* __restrict__ out,
                      int N, int NT, int KW, int MROW) {
    __shared__ unsigned short As[128][32];
    __shared__ unsigned short Bs[128][32];
    const int tid  = threadIdx.x;
    const int row0 = blockIdx.x * 128;
    const int lane = tid & 63;
    const int wid  = tid >> 6;
    const int wm   = wid >> 1;         // wave grid 2x2, each wave 64x64
    const int wn   = wid & 1;
    const int srow = tid >> 1;         // staging row 0..127
    const int sh16 = (tid & 1) * 16;   // staging k-offset (elems)

    f32x4 acc[4][4] = {};

    const int  node = row0 + srow;
    const bool nok  = node < N;

    for (int kt = 0; kt < NT; ++kt) {
        if (kt) __syncthreads();
        u16x8 a0, a1;
        #pragma unroll
        for (int j = 0; j < 8; ++j) { a0[j] = 0; a1[j] = 0; }
        if (FIRST && kt < 4) {
            if (nok) {
                const float4* xp = (const float4*)(x + (size_t)node * 128 + kt * 32 + sh16);
                float4 v0 = xp[0], v1 = xp[1], v2 = xp[2], v3 = xp[3];
                a0[0] = f2bf(v0.x); a0[1] = f2bf(v0.y); a0[2] = f2bf(v0.z); a0[3] = f2bf(v0.w);
                a0[4] = f2bf(v1.x); a0[5] = f2bf(v1.y); a0[6] = f2bf(v1.z); a0[7] = f2bf(v1.w);
                a1[0] = f2bf(v2.x); a1[1] = f2bf(v2.y); a1[2] = f2bf(v2.z); a1[3] = f2bf(v2.w);
                a1[4] = f2bf(v3.x); a1[5] = f2bf(v3.y); a1[6] = f2bf(v3.z); a1[7] = f2bf(v3.w);
            }
        } else {
            if (nok) {
                const u16x8* mp = (const u16x8*)(mean + (size_t)node * MROW
                                                 + (kt - (FIRST ? 4 : 0)) * 32 + sh16);
                a0 = mp[0]; a1 = mp[1];
            }
        }
        const u16x8* wp = (const u16x8*)(WallTc + (size_t)srow * KW + kt * 32 + sh16);
        u16x8 b0 = wp[0], b1 = wp[1];

        *(u16x8*)&As[srow][sh16]     = a0;
        *(u16x8*)&As[srow][sh16 + 8] = a1;
        *(u16x8*)&Bs[srow][sh16]     = b0;
        *(u16x8*)&Bs[srow][sh16 + 8] = b1;
        __syncthreads();

        const int kg = (lane >> 4) * 8;
        const int rl = lane & 15;
        bf16x8 av[4], bv[4];
        #pragma unroll
        for (int f = 0; f < 4; ++f) {
            av[f] = __builtin_bit_cast(bf16x8, *(const u16x8*)&As[wm * 64 + f * 16 + rl][kg]);
            bv[f] = __builtin_bit_cast(bf16x8, *(const u16x8*)&Bs[wn * 64 + f * 16 + rl][kg]);
        }
        #pragma unroll
        for (int mf = 0; mf < 4; ++mf)
            #pragma unroll
            for (int nf = 0; nf < 4; ++nf)
                acc[mf][nf] = __builtin_amdgcn_mfma_f32_16x16x32_bf16(av[mf], bv[nf],
                                                                     acc[mf][nf], 0, 0, 0);
    }

    // epilogue: C/D layout (m89): n = lane&15 (+16*nf+64*wn), m = (lane>>4)*4 + i
    const int rl = lane & 15;
    const int rg = lane >> 4;
    #pragma unroll
    for (int nf = 0; nf < 4; ++nf) {
        int n = wn * 64 + nf * 16 + rl;
        float bb = FIRST ? bias[n] : 0.0f;
        #pragma unroll
        for (int mf = 0; mf < 4; ++mf) {
            #pragma unroll
            for (int i = 0; i < 4; ++i) {
                int nd = row0 + wm * 64 + mf * 16 + rg * 4 + i;
                if (nd < N) {
                    size_t o = (size_t)nd * 128 + n;
                    if (FIRST) out[o] = acc[mf][nf][i] + bb;
                    else       out[o] += acc[mf][nf][i];
                }
            }
        }
    }
}

extern "C" void kernel_launch(void* const* d_in, const int* in_sizes, int n_in,
                              void* d_out, int out_size, void* d_ws, size_t ws_size,
                              hipStream_t stream) {
    const float* x     = (const float*)d_in[0];
    const float* W     = (const float*)d_in[1];
    const float* Wroot = (const float*)d_in[2];
    const float* bias  = (const float*)d_in[3];
    const int*   ei    = (const int*)d_in[4];
    const int*   et    = (const int*)d_in[5];
    float*       out   = (float*)d_out;

    const int N = in_sizes[0] / D;
    const int E = in_sizes[5];
    const int* src = ei;
    const int* dst = ei + E;

    const int NSEG = N * R;
    const int NB   = (NSEG + 256) / 256;   // scan grid covers index i == NSEG

    // fixed int area: hstart(NSEG+1) + cursor(NSEG) + spack(E) + bsum(NB)
    const size_t fixed_bytes = ((size_t)(NSEG + 1) + NSEG + E + NB) * 4;
    const size_t walltc_max  = (size_t)128 * 1152 * 2;     // 294912

    int CW = 0, tshift = 0;
    const int cands[4]  = {128, 64, 32, 16};
    const int tshifts[4] = {5, 4, 3, 2};
    for (int i = 0; i < 4; ++i) {
        size_t need = (size_t)NSEG * cands[i] * 2 + walltc_max + fixed_bytes + 256;
        if (need <= ws_size) { CW = cands[i]; tshift = tshifts[i]; break; }
    }
    if (CW == 0) return;

    char* p = (char*)d_ws;
    unsigned short* mean   = (unsigned short*)p;  p += (size_t)NSEG * CW * 2;
    unsigned short* WallTc = (unsigned short*)p;  p += walltc_max;
    int* hstart = (int*)p;  p += (size_t)(NSEG + 1) * 4;
    int* cursor = (int*)p;  p += (size_t)NSEG * 4;
    int* spack  = (int*)p;  p += (size_t)E * 4;
    int* bsum   = (int*)p;

    // ---- sort by seg (once) ----
    hipMemsetAsync(hstart, 0, (size_t)(NSEG + 1) * 4, stream);
    hist_kernel<<<(E + 255) / 256, 256, 0, stream>>>(dst, et, hstart, E);
    block_sums_kernel<<<NB, 256, 0, stream>>>(hstart, bsum, NSEG);
    scan_bsum_kernel<<<1, 64, 0, stream>>>(bsum, NB);
    scan_block_kernel<<<NB, 256, 0, stream>>>(hstart, bsum, cursor, NSEG, E);
    reorder_kernel<<<(E + 255) / 256, 256, 0, stream>>>(src, dst, et, cursor, spack, E);

    // ---- per feature-chunk: aggregate + MFMA GEMM ----
    const int gx   = (N + 127) / 128;
    const int nch  = D / CW;
    for (int c = 0; c < nch; ++c) {
        int c0    = c * CW;
        int first = (c == 0);
        long long aggth = (long long)NSEG << tshift;
        aggregate_kernel<<<(int)((aggth + 255) / 256), 256, 0, stream>>>(
            x, spack, hstart, mean, NSEG, tshift, c0);
        int KW   = (first ? 128 : 0) + R * CW;
        int NT   = KW / 32;
        int MROW = R * CW;
        wallt_kernel<<<(128 * KW + 255) / 256, 256, 0, stream>>>(
            Wroot, W, WallTc, KW, CW, c0, first);
        if (first)
            mfma_gemm_kernel<true><<<gx, 256, 0, stream>>>(
                x, mean, WallTc, bias, out, N, NT, KW, MROW);
        else
            mfma_gemm_kernel<false><<<gx, 256, 0, stream>>>(
                x, mean, WallTc, bias, out, N, NT, KW, MROW);
    }
}